// Round 4
// baseline (94.419 us; speedup 1.0000x reference)
//
#include <hip/hip_runtime.h>
#include <hip/hip_bf16.h>

// Masked SDPA, B=16, NQ=NKV=2048, D=64, f32 in/out, bf16 MFMA compute.
// R4: swapped QK^T (S^T in regs -> mostly in-lane softmax, 2 shuffles/tile),
// T13 defer-max, KV-split into 4 chunks of 512 + combine pass (load balance +
// occupancy), T14 async staging kept, swizzled LDS kept.

typedef __attribute__((ext_vector_type(8))) short short8;
typedef __attribute__((ext_vector_type(4))) short short4v;
typedef __attribute__((ext_vector_type(4))) float float4v;

#define BATCH 16
#define NQ 2048
#define NKV 2048
#define DH 64
#define KVB 64
#define NEG_INF -1e20f
// (1/sqrt(64)) * log2(e): softmax in base 2
#define SCALE_LOG2 0.180336880111120f

__device__ __forceinline__ short f2bf(float x) {
    union { float f; unsigned u; } v; v.f = x;
    unsigned r = (v.u + 0x7fffu + ((v.u >> 16) & 1u)) >> 16;
    return (short)r;
}

__device__ __forceinline__ short8 cvt8(float4v a, float4v b) {
    short8 r;
    r[0] = f2bf(a[0]); r[1] = f2bf(a[1]); r[2] = f2bf(a[2]); r[3] = f2bf(a[3]);
    r[4] = f2bf(b[0]); r[5] = f2bf(b[1]); r[6] = f2bf(b[2]); r[7] = f2bf(b[3]);
    return r;
}

__global__ __launch_bounds__(256) void attn_fwd_kernel(
    const float* __restrict__ Q,
    const float* __restrict__ K,
    const float* __restrict__ V,
    const int* __restrict__ valid_lens,
    float* __restrict__ Op,      // partials [ch][b][q][d] (undivided)
    float2* __restrict__ ml,     // [ch][b][q] = (m_log2, lsum)
    float* __restrict__ Ofinal,  // direct output when nch==1
    int nch)
{
    __shared__ short k_lds[KVB * DH];     // K tile [kv][d], swizzled
    __shared__ short vt_lds[DH * KVB];    // V^T tile [d][kv], swizzled
    __shared__ short p_lds[4][16 * KVB];  // per-wave P tile [q][kv], swizzled

    const int tid  = threadIdx.x;
    const int wave = tid >> 6;
    const int lane = tid & 63;
    const int l15  = lane & 15;
    const int l4   = lane >> 4;
    const int tb   = (lane & 48) | (l4 << 2);  // same-quarter transpose base

    const int ch  = blockIdx.x >> 9;       // 512 blocks per chunk
    const int rem = blockIdx.x & 511;
    const int b   = rem & 15;
    const int qt  = rem >> 4;              // 0..31
    const int qbase = qt * 64 + wave * 16;

    const int vlen = valid_lens[b];
    const int nkv  = (vlen == 0) ? NKV : vlen;  // all-masked -> uniform
    const int chunk = NKV / nch;
    const int cbase = ch * chunk;

    if (cbase >= nkv) {                    // inactive chunk
        if (nch > 1 && tid < 64)
            ml[(size_t)ch * BATCH * NQ + (size_t)b * NQ + qt * 64 + tid] =
                float2{-INFINITY, 0.f};
        return;
    }
    const int kvlen = min(nkv - cbase, chunk);
    const int niter = (kvlen + KVB - 1) / KVB;

    const float* Qb = Q + ((size_t)b * NQ + qbase) * DH;
    const float* Kc = K + ((size_t)b * NKV + cbase) * DH;
    const float* Vc = V + ((size_t)b * NKV + cbase) * DH;

    // Q B-fragment: lane col q=l15, k-elems d = h*32 + l4*8 + j
    short8 qfrag[2];
#pragma unroll
    for (int h = 0; h < 2; ++h) {
        const float* p = Qb + (size_t)l15 * DH + h * 32 + l4 * 8;
        qfrag[h] = cvt8(*reinterpret_cast<const float4v*>(p),
                        *reinterpret_cast<const float4v*>(p + 4));
    }

    // staging coordinates
    const int krow = tid >> 2;             // 0..63
    const int kcol = (tid & 3) << 4;       // 0,16,32,48
    const int vkv  = (tid >> 4) << 2;      // 0..60 step 4
    const int vd   = (tid & 15) << 2;      // 0..60 step 4

    float4v kr[4], vr[4];
    auto load_tile = [&](int kvloc) {
        const float* kp = Kc + (size_t)(kvloc + krow) * DH + kcol;
#pragma unroll
        for (int i = 0; i < 4; ++i)
            kr[i] = *reinterpret_cast<const float4v*>(kp + i * 4);
        const float* vp = Vc + (size_t)(kvloc + vkv) * DH + vd;
#pragma unroll
        for (int i = 0; i < 4; ++i)
            vr[i] = *reinterpret_cast<const float4v*>(vp + (size_t)i * DH);
    };
    auto store_tile = [&]() {
        const int ksw = (krow & 7) << 3;
        *reinterpret_cast<short8*>(&k_lds[krow * DH + (kcol ^ ksw)]) =
            cvt8(kr[0], kr[1]);
        *reinterpret_cast<short8*>(&k_lds[krow * DH + ((kcol + 8) ^ ksw)]) =
            cvt8(kr[2], kr[3]);
#pragma unroll
        for (int k = 0; k < 4; ++k) {
            const int d = vd + k;
            short4v w;
            w[0] = f2bf(vr[0][k]); w[1] = f2bf(vr[1][k]);
            w[2] = f2bf(vr[2][k]); w[3] = f2bf(vr[3][k]);
            *reinterpret_cast<short4v*>(
                &vt_lds[d * KVB + (vkv ^ ((d & 7) << 3))]) = w;
        }
    };

    float4v acc_o[4];
#pragma unroll
    for (int t = 0; t < 4; ++t) acc_o[t] = float4v{0.f, 0.f, 0.f, 0.f};
    float m = -INFINITY, lsum = 0.f;

    load_tile(0);
    store_tile();
    __syncthreads();

    const int rsw = (l15 & 7) << 3;        // read-side swizzle

    for (int it = 0; it < niter; ++it) {
        const int kvloc = it * KVB;
        const bool more = (it + 1 < niter);
        if (more) load_tile(kvloc + KVB);  // T14: issue early, write late

        // ---- S^T = (K Q^T): 4 subtiles; lane owns q=l15, kv=s*16+l4*4+r ----
        float4v accs[4];
#pragma unroll
        for (int s = 0; s < 4; ++s) accs[s] = float4v{0.f, 0.f, 0.f, 0.f};
#pragma unroll
        for (int s = 0; s < 4; ++s) {
            const short* kb = &k_lds[(s * 16 + l15) * DH];
#pragma unroll
            for (int h = 0; h < 2; ++h) {
                short8 kf = *reinterpret_cast<const short8*>(
                    &kb[(h * 32 + l4 * 8) ^ rsw]);
                accs[s] = __builtin_amdgcn_mfma_f32_16x16x32_bf16(
                    kf, qfrag[h], accs[s], 0, 0, 0);
            }
        }

        // ---- scale (log2) + mask; all values for q=l15 are in-lane ----
        const int vlim = vlen - (cbase + kvloc + l4 * 4);
        float sv[4][4];
#pragma unroll
        for (int s = 0; s < 4; ++s)
#pragma unroll
            for (int r = 0; r < 4; ++r)
                sv[s][r] = (s * 16 + r) < vlim ? accs[s][r] * SCALE_LOG2
                                               : NEG_INF;

        // ---- tile max: 15 in-lane + 2 shuffles ----
        float x = sv[0][0];
#pragma unroll
        for (int s = 0; s < 4; ++s)
#pragma unroll
            for (int r = 0; r < 4; ++r) x = fmaxf(x, sv[s][r]);
        x = fmaxf(x, __shfl_xor(x, 16, 64));
        x = fmaxf(x, __shfl_xor(x, 32, 64));

        // ---- T13 defer-max ----
        float mn = m;
        if (!__all(x <= m + 8.f)) {
            mn = fmaxf(m, x);
            const float alpha = exp2f(m - mn);   // m=-inf first iter -> 0
            m = mn;
            lsum *= alpha;
            float ar[4];
#pragma unroll
            for (int r = 0; r < 4; ++r) ar[r] = __shfl(alpha, tb + r, 64);
#pragma unroll
            for (int t = 0; t < 4; ++t)
#pragma unroll
                for (int r = 0; r < 4; ++r) acc_o[t][r] *= ar[r];
        }

        // ---- P = exp2(sv - mn), in-lane sum + 2 shuffles ----
        float rsum = 0.f;
#pragma unroll
        for (int s = 0; s < 4; ++s)
#pragma unroll
            for (int r = 0; r < 4; ++r) {
                const float p = exp2f(sv[s][r] - mn);
                sv[s][r] = p;
                rsum += p;
            }
        rsum += __shfl_xor(rsum, 16, 64);
        rsum += __shfl_xor(rsum, 32, 64);
        lsum += rsum;

        // ---- P -> bf16 -> per-wave swizzled LDS (4x ds_write_b64) ----
        short* pw = p_lds[wave];
#pragma unroll
        for (int s = 0; s < 4; ++s) {
            short4v w;
            w[0] = f2bf(sv[s][0]); w[1] = f2bf(sv[s][1]);
            w[2] = f2bf(sv[s][2]); w[3] = f2bf(sv[s][3]);
            *reinterpret_cast<short4v*>(
                &pw[l15 * KVB + ((s * 16 + l4 * 4) ^ ((l15 & 7) << 3))]) = w;
        }
        asm volatile("s_waitcnt lgkmcnt(0)" ::: "memory");
        short8 pf[2];
#pragma unroll
        for (int ks = 0; ks < 2; ++ks)
            pf[ks] = *reinterpret_cast<const short8*>(
                &pw[l15 * KVB + ((ks * 32 + l4 * 8) ^ rsw)]);

        // ---- O += P V ----
#pragma unroll
        for (int t = 0; t < 4; ++t) {
            const short* vb2 = &vt_lds[(t * 16 + l15) * KVB];
#pragma unroll
            for (int ks = 0; ks < 2; ++ks) {
                short8 vf = *reinterpret_cast<const short8*>(
                    &vb2[(ks * 32 + l4 * 8) ^ rsw]);
                acc_o[t] = __builtin_amdgcn_mfma_f32_16x16x32_bf16(
                    pf[ks], vf, acc_o[t], 0, 0, 0);
            }
        }

        __syncthreads();
        if (more) store_tile();
        __syncthreads();
    }

    if (nch == 1) {
        float lr[4];
#pragma unroll
        for (int r = 0; r < 4; ++r) lr[r] = __shfl(lsum, tb + r, 64);
        float* Ob = Ofinal + ((size_t)b * NQ + qbase) * DH;
#pragma unroll
        for (int t = 0; t < 4; ++t)
#pragma unroll
            for (int r = 0; r < 4; ++r)
                Ob[(size_t)(l4 * 4 + r) * DH + t * 16 + l15] =
                    acc_o[t][r] / lr[r];
    } else {
        float* Ob = Op + ((size_t)ch * BATCH * NQ + (size_t)b * NQ + qbase) * DH;
#pragma unroll
        for (int t = 0; t < 4; ++t)
#pragma unroll
            for (int r = 0; r < 4; ++r)
                Ob[(size_t)(l4 * 4 + r) * DH + t * 16 + l15] = acc_o[t][r];
        if (l4 == 0)
            ml[(size_t)ch * BATCH * NQ + (size_t)b * NQ + qbase + l15] =
                float2{m, lsum};
    }
}

__global__ __launch_bounds__(256) void combine_kernel(
    const float* __restrict__ Op, const float2* __restrict__ ml,
    float* __restrict__ O, int nch)
{
    const int g  = blockIdx.x * 256 + threadIdx.x;  // 0 .. B*NQ*16-1
    const int bq = g >> 4;
    const int d4 = (g & 15) << 2;

    float2 c[8];
    float M = -INFINITY;
    for (int i = 0; i < nch; ++i) {
        c[i] = ml[(size_t)i * BATCH * NQ + bq];
        if (c[i].y > 0.f) M = fmaxf(M, c[i].x);
    }
    float wsum = 0.f;
    float4v acc = float4v{0.f, 0.f, 0.f, 0.f};
    for (int i = 0; i < nch; ++i) {
        if (c[i].y > 0.f) {
            const float w = exp2f(c[i].x - M);
            wsum += w * c[i].y;
            float4v v = *reinterpret_cast<const float4v*>(
                Op + ((size_t)i * BATCH * NQ + bq) * DH + d4);
            acc[0] += w * v[0]; acc[1] += w * v[1];
            acc[2] += w * v[2]; acc[3] += w * v[3];
        }
    }
    const float inv = 1.f / wsum;
    float4v out;
    out[0] = acc[0] * inv; out[1] = acc[1] * inv;
    out[2] = acc[2] * inv; out[3] = acc[3] * inv;
    *reinterpret_cast<float4v*>(O + (size_t)bq * DH + d4) = out;
}

extern "C" void kernel_launch(void* const* d_in, const int* in_sizes, int n_in,
                              void* d_out, int out_size, void* d_ws, size_t ws_size,
                              hipStream_t stream) {
    const float* Q = (const float*)d_in[0];
    const float* K = (const float*)d_in[1];
    const float* V = (const float*)d_in[2];
    const int* vl  = (const int*)d_in[3];
    float* Out     = (float*)d_out;

    const int NCH = 4;
    const size_t op_bytes = (size_t)NCH * BATCH * NQ * DH * sizeof(float);
    const size_t ml_bytes = (size_t)NCH * BATCH * NQ * sizeof(float2);
    int nch = (ws_size >= op_bytes + ml_bytes) ? NCH : 1;

    float*  Op  = (float*)d_ws;
    float2* mlp = (float2*)((char*)d_ws +
                            (size_t)nch * BATCH * NQ * DH * sizeof(float));

    dim3 block(256);
    attn_fwd_kernel<<<dim3(512 * nch), block, 0, stream>>>(
        Q, K, V, vl, Op, mlp, Out, nch);
    if (nch > 1)
        combine_kernel<<<dim3((BATCH * NQ * 16) / 256), block, 0, stream>>>(
            Op, mlp, Out, nch);
}

// Round 5
// 50.206 us; speedup vs baseline: 1.8806x; 1.8806x over previous
//
#include <hip/hip_runtime.h>
#include <hip/hip_bf16.h>

// Masked SDPA, B=16, NQ=NKV=2048, D=64, f32 in/out, bf16 MFMA compute.
// R5: (1) prep pass converts K/V to bf16 in tile-swizzled (K) and
// transposed+swizzled (V) layouts in d_ws -- conversion paid once, not 32x;
// (2) attn stages tiles via global_load_lds (zero-VALU staging, pre-swizzled
// source / linear LDS dest per m173); (3) in-block KV split: 8 waves =
// 4 q-subtiles x 2 KV halves (interleaved tiles), merged in LDS epilogue --
// no combine kernel; (4) scale folded into Q pre-cast; setprio around MFMA.

typedef __attribute__((ext_vector_type(8))) short short8;
typedef __attribute__((ext_vector_type(4))) short short4v;
typedef __attribute__((ext_vector_type(4))) float float4v;

#define BATCH 16
#define NQ 2048
#define NKV 2048
#define DH 64
#define KVB 64
#define NTILES (NKV / KVB)          // 32
#define TILE_ELEMS (KVB * DH)       // 4096 bf16 elems = 8 KB
#define NEG_INF -1e20f
// (1/sqrt(64)) * log2(e): softmax in base 2
#define SCALE_LOG2 0.180336880111120f

__device__ __forceinline__ short f2bf(float x) {
    union { float f; unsigned u; } v; v.f = x;
    unsigned r = (v.u + 0x7fffu + ((v.u >> 16) & 1u)) >> 16;
    return (short)r;
}

__device__ __forceinline__ short8 cvt8(float4v a, float4v b) {
    short8 r;
    r[0] = f2bf(a[0]); r[1] = f2bf(a[1]); r[2] = f2bf(a[2]); r[3] = f2bf(a[3]);
    r[4] = f2bf(b[0]); r[5] = f2bf(b[1]); r[6] = f2bf(b[2]); r[7] = f2bf(b[3]);
    return r;
}

// async global->LDS, 16B per lane (dest must be wave-uniform base + lane*16)
__device__ __forceinline__ void gll16(const short* g, short* l) {
    __builtin_amdgcn_global_load_lds(
        (const __attribute__((address_space(1))) unsigned int*)g,
        (__attribute__((address_space(3))) unsigned int*)l, 16, 0, 0);
}

// ---------------- prep: f32 -> bf16, LDS-image layouts in ws ----------------
__global__ __launch_bounds__(256) void prep_kernel(
    const float* __restrict__ K, const float* __restrict__ V,
    const int* __restrict__ valid_lens,
    short* __restrict__ Kws, short* __restrict__ Vws)
{
    const int b    = blockIdx.x >> 5;
    const int tile = blockIdx.x & 31;
    const int vlen = valid_lens[b];
    const int nkv  = (vlen == 0) ? NKV : vlen;
    if (tile * KVB >= nkv) return;          // never read by attn

    const int tid = threadIdx.x;
    const size_t gbase = ((size_t)b * NKV + (size_t)tile * KVB) * DH;
    short* kt = Kws + (((size_t)b * NTILES + tile) * TILE_ELEMS);
    short* vt = Vws + (((size_t)b * NTILES + tile) * TILE_ELEMS);

    {   // K: row-major [kv][d], col XOR-swizzled by (row&7)<<3
        const int row = tid >> 2;
        const int col = (tid & 3) << 4;
        const float* p = K + gbase + (size_t)row * DH + col;
        float4v a0 = *reinterpret_cast<const float4v*>(p);
        float4v a1 = *reinterpret_cast<const float4v*>(p + 4);
        float4v a2 = *reinterpret_cast<const float4v*>(p + 8);
        float4v a3 = *reinterpret_cast<const float4v*>(p + 12);
        const int sw = (row & 7) << 3;
        *reinterpret_cast<short8*>(&kt[row * DH + (col ^ sw)])       = cvt8(a0, a1);
        *reinterpret_cast<short8*>(&kt[row * DH + ((col + 8) ^ sw)]) = cvt8(a2, a3);
    }
    {   // V: transposed [d][kv], kv XOR-swizzled by (d&7)<<3
        const int kv = (tid >> 4) << 2;
        const int d  = (tid & 15) << 2;
        const float* p = V + gbase + (size_t)kv * DH + d;
        float4v r0 = *reinterpret_cast<const float4v*>(p);
        float4v r1 = *reinterpret_cast<const float4v*>(p + DH);
        float4v r2 = *reinterpret_cast<const float4v*>(p + 2 * DH);
        float4v r3 = *reinterpret_cast<const float4v*>(p + 3 * DH);
#pragma unroll
        for (int k = 0; k < 4; ++k) {
            const int dd = d + k;
            short4v w;
            w[0] = f2bf(r0[k]); w[1] = f2bf(r1[k]);
            w[2] = f2bf(r2[k]); w[3] = f2bf(r3[k]);
            *reinterpret_cast<short4v*>(
                &vt[dd * KVB + (kv ^ ((dd & 7) << 3))]) = w;
        }
    }
}

// ---------------- attn: 8 waves = 4 q-subtiles x 2 KV halves ----------------
__global__ __launch_bounds__(512) void attn_fwd_kernel(
    const float* __restrict__ Q,
    const short* __restrict__ Kws,
    const short* __restrict__ Vws,
    const int* __restrict__ valid_lens,
    float* __restrict__ O)
{
    __shared__ __align__(16) short k_lds[2][TILE_ELEMS];   // per-half K tile
    __shared__ __align__(16) short v_lds[2][TILE_ELEMS];   // per-half V^T tile
    __shared__ __align__(16) short p_lds[8][16 * KVB];     // per-wave P; merge buf
    __shared__ float2 ml_sh[4][16];

    const int tid  = threadIdx.x;
    const int wave = tid >> 6;
    const int lane = tid & 63;
    const int l15  = lane & 15;
    const int l4   = lane >> 4;
    const int h    = wave >> 2;            // KV half
    const int qsub = wave & 3;             // q sub-tile
    const int tb   = (lane & 48) | (l4 << 2);

    const int b  = blockIdx.x & 15;
    const int qt = blockIdx.x >> 4;        // 0..31
    const int qbase = qt * 64 + qsub * 16;

    const int vlen  = valid_lens[b];
    const int nkv   = (vlen == 0) ? NKV : vlen;
    const int tiles = (nkv + KVB - 1) / KVB;
    const int nh = (tiles + 1 - h) >> 1;   // my half's tile count (interleaved)
    const int n0 = (tiles + 1) >> 1;       // loop bound (max over halves)

    // Q B-fragment, scale pre-folded: lane col q=l15, k d = h2*32 + l4*8 + j
    const float* Qb = Q + ((size_t)b * NQ + qbase) * DH;
    short8 qfrag[2];
#pragma unroll
    for (int h2 = 0; h2 < 2; ++h2) {
        const float* p = Qb + (size_t)l15 * DH + h2 * 32 + l4 * 8;
        float4v a = *reinterpret_cast<const float4v*>(p);
        float4v c = *reinterpret_cast<const float4v*>(p + 4);
#pragma unroll
        for (int j = 0; j < 4; ++j) { a[j] *= SCALE_LOG2; c[j] *= SCALE_LOG2; }
        qfrag[h2] = cvt8(a, c);
    }

    const short* Kb = Kws + ((size_t)b * NTILES) * TILE_ELEMS;
    const short* Vb = Vws + ((size_t)b * NTILES) * TILE_ELEMS;
    short* kds = k_lds[h];
    short* vds = v_lds[h];
    const int soff = qsub * 512 + lane * 8;     // elems; per-wave-uniform base

    auto stage = [&](int tile) {
        const short* kp = Kb + (size_t)tile * TILE_ELEMS + soff;
        const short* vp = Vb + (size_t)tile * TILE_ELEMS + soff;
        gll16(kp,        kds + soff);
        gll16(kp + 2048, kds + 2048 + soff);
        gll16(vp,        vds + soff);
        gll16(vp + 2048, vds + 2048 + soff);
    };

    float4v acc_o[4];
#pragma unroll
    for (int t = 0; t < 4; ++t) acc_o[t] = float4v{0.f, 0.f, 0.f, 0.f};
    float m = -INFINITY, lsum = 0.f;

    if (nh > 0) stage(h);                   // first tile of my half (0 or 1)
    asm volatile("s_waitcnt vmcnt(0)" ::: "memory");
    __syncthreads();

    const int rsw = (l15 & 7) << 3;         // read-side swizzle

    for (int it = 0; it < n0; ++it) {
        if (it < nh) {
            const int tile = 2 * it + h;

            // ---- S^T = K Q^T (scale in Q): lane owns q=l15, kv=s*16+l4*4+r
            float4v accs[4];
#pragma unroll
            for (int s = 0; s < 4; ++s) accs[s] = float4v{0.f, 0.f, 0.f, 0.f};
            __builtin_amdgcn_s_setprio(1);
#pragma unroll
            for (int s = 0; s < 4; ++s) {
                const short* kb = &kds[(s * 16 + l15) * DH];
#pragma unroll
                for (int h2 = 0; h2 < 2; ++h2) {
                    short8 kf = *reinterpret_cast<const short8*>(
                        &kb[(h2 * 32 + l4 * 8) ^ rsw]);
                    accs[s] = __builtin_amdgcn_mfma_f32_16x16x32_bf16(
                        kf, qfrag[h2], accs[s], 0, 0, 0);
                }
            }
            __builtin_amdgcn_s_setprio(0);

            // ---- mask (already log2 units) ----
            const int vlim = vlen - (tile * KVB + l4 * 4);
            float sv[4][4];
#pragma unroll
            for (int s = 0; s < 4; ++s)
#pragma unroll
                for (int r = 0; r < 4; ++r)
                    sv[s][r] = (s * 16 + r) < vlim ? accs[s][r] : NEG_INF;

            // ---- tile max: 15 in-lane + 2 shuffles ----
            float x = sv[0][0];
#pragma unroll
            for (int s = 0; s < 4; ++s)
#pragma unroll
                for (int r = 0; r < 4; ++r) x = fmaxf(x, sv[s][r]);
            x = fmaxf(x, __shfl_xor(x, 16, 64));
            x = fmaxf(x, __shfl_xor(x, 32, 64));

            // ---- T13 defer-max ----
            float mn = m;
            if (!__all(x <= m + 8.f)) {
                mn = fmaxf(m, x);
                const float alpha = exp2f(m - mn);   // m=-inf first -> 0
                m = mn;
                lsum *= alpha;
                float ar[4];
#pragma unroll
                for (int r = 0; r < 4; ++r) ar[r] = __shfl(alpha, tb + r, 64);
#pragma unroll
                for (int t = 0; t < 4; ++t)
#pragma unroll
                    for (int r = 0; r < 4; ++r) acc_o[t][r] *= ar[r];
            }

            // ---- P = exp2(sv - mn), in-lane sum + 2 shuffles ----
            float rsum = 0.f;
#pragma unroll
            for (int s = 0; s < 4; ++s)
#pragma unroll
                for (int r = 0; r < 4; ++r) {
                    const float p = exp2f(sv[s][r] - mn);
                    sv[s][r] = p;
                    rsum += p;
                }
            rsum += __shfl_xor(rsum, 16, 64);
            rsum += __shfl_xor(rsum, 32, 64);
            lsum += rsum;

            // ---- P -> bf16 -> per-wave swizzled LDS ----
            short* pw = p_lds[wave];
#pragma unroll
            for (int s = 0; s < 4; ++s) {
                short4v w;
                w[0] = f2bf(sv[s][0]); w[1] = f2bf(sv[s][1]);
                w[2] = f2bf(sv[s][2]); w[3] = f2bf(sv[s][3]);
                *reinterpret_cast<short4v*>(
                    &pw[l15 * KVB + ((s * 16 + l4 * 4) ^ ((l15 & 7) << 3))]) = w;
            }
            asm volatile("s_waitcnt lgkmcnt(0)" ::: "memory");
            short8 pf[2];
#pragma unroll
            for (int ks = 0; ks < 2; ++ks)
                pf[ks] = *reinterpret_cast<const short8*>(
                    &pw[l15 * KVB + ((ks * 32 + l4 * 8) ^ rsw)]);

            // ---- O += P V ----
            __builtin_amdgcn_s_setprio(1);
#pragma unroll
            for (int t = 0; t < 4; ++t) {
                const short* vb2 = &vds[(t * 16 + l15) * KVB];
#pragma unroll
                for (int ks = 0; ks < 2; ++ks) {
                    short8 vf = *reinterpret_cast<const short8*>(
                        &vb2[(ks * 32 + l4 * 8) ^ rsw]);
                    acc_o[t] = __builtin_amdgcn_mfma_f32_16x16x32_bf16(
                        pf[ks], vf, acc_o[t], 0, 0, 0);
                }
            }
            __builtin_amdgcn_s_setprio(0);
        }

        __syncthreads();                    // group done reading LDS tile
        if (it + 1 < nh) stage(2 * (it + 1) + h);
        asm volatile("s_waitcnt vmcnt(0)" ::: "memory");
        __syncthreads();                    // staged tile visible
    }

    // ---- merge the two KV halves in LDS; half 0 writes output ----
    float* mrg = reinterpret_cast<float*>(p_lds);   // 4096 f32 = all of p_lds
    if (h == 1) {
#pragma unroll
        for (int t = 0; t < 4; ++t)
            *reinterpret_cast<float4v*>(
                &mrg[qsub * 1024 + t * 256 + lane * 4]) = acc_o[t];
        if (l4 == 0) ml_sh[qsub][l15] = float2{m, lsum};
    }
    __syncthreads();
    if (h == 0) {
        const float2 o1 = ml_sh[qsub][l15];
        const float m1 = o1.x, l1 = o1.y;
        const float M  = (l1 > 0.f) ? fmaxf(m, m1) : m;
        const float w0 = exp2f(m - M);
        const float w1 = (l1 > 0.f) ? exp2f(m1 - M) : 0.f;
        const float L  = lsum * w0 + l1 * w1;
        const float a0 = w0 / L, a1 = w1 / L;
        float a0r[4], a1r[4];
#pragma unroll
        for (int r = 0; r < 4; ++r) {
            a0r[r] = __shfl(a0, tb + r, 64);
            a1r[r] = __shfl(a1, tb + r, 64);
        }
        float* Ob = O + ((size_t)b * NQ + qbase) * DH;
#pragma unroll
        for (int t = 0; t < 4; ++t) {
            float4v oh = *reinterpret_cast<const float4v*>(
                &mrg[qsub * 1024 + t * 256 + lane * 4]);
#pragma unroll
            for (int r = 0; r < 4; ++r)
                Ob[(size_t)(l4 * 4 + r) * DH + t * 16 + l15] =
                    acc_o[t][r] * a0r[r] + oh[r] * a1r[r];
        }
    }
}

extern "C" void kernel_launch(void* const* d_in, const int* in_sizes, int n_in,
                              void* d_out, int out_size, void* d_ws, size_t ws_size,
                              hipStream_t stream) {
    const float* Q = (const float*)d_in[0];
    const float* K = (const float*)d_in[1];
    const float* V = (const float*)d_in[2];
    const int* vl  = (const int*)d_in[3];
    float* Out     = (float*)d_out;

    short* Kws = (short*)d_ws;
    short* Vws = Kws + (size_t)BATCH * NTILES * TILE_ELEMS;

    prep_kernel<<<dim3(BATCH * NTILES), dim3(256), 0, stream>>>(K, V, vl, Kws, Vws);
    attn_fwd_kernel<<<dim3(512), dim3(512), 0, stream>>>(Q, Kws, Vws, vl, Out);
}